// Round 1
// baseline (1649.548 us; speedup 1.0000x reference)
//
#include <hip/hip_runtime.h>

typedef unsigned int uint;
typedef unsigned short ushort;
typedef __attribute__((ext_vector_type(8))) short bf16x8;
typedef __attribute__((ext_vector_type(4))) float f32x4;

#define HWSZ 65536
#define CIN 192
#define C3 576
#define CQK 384

typedef __attribute__((address_space(1))) const void gvoid_c;
typedef __attribute__((address_space(3))) void lvoid;

__device__ __forceinline__ void async16(void* l, const void* g) {
  __builtin_amdgcn_global_load_lds((gvoid_c*)g, (lvoid*)l, 16, 0, 0);
}

__device__ __forceinline__ ushort f2bf(float f) {
  uint u = __float_as_uint(f);
  return (ushort)((u + 0x7fffu + ((u >> 16) & 1u)) >> 16);
}
__device__ __forceinline__ float bflo(uint u) { return __uint_as_float(u << 16); }
__device__ __forceinline__ float bfhi(uint u) { return __uint_as_float(u & 0xffff0000u); }

// ---------------- K0a: x fp32 [b][c][n] -> bf16 [b][n][c] ----------------
__global__ __launch_bounds__(256) void k0_transpose(const float* __restrict__ x,
                                                    ushort* __restrict__ xT) {
  int id = blockIdx.x;
  int n0 = (id & 1023) << 6;
  int b = id >> 10;
  int nl = threadIdx.x & 63;
  int c8b = threadIdx.x >> 6;
  const float* xb = x + (long)b * CIN * HWSZ;
  ushort* ob = xT + (long)b * HWSZ * CIN;
  int n = n0 + nl;
#pragma unroll
  for (int j = 0; j < 6; ++j) {
    int c8 = c8b + 4 * j;  // 0..23
    ushort v[8];
#pragma unroll
    for (int jj = 0; jj < 8; ++jj)
      v[jj] = f2bf(xb[(long)(c8 * 8 + jj) * HWSZ + n]);
    uint4 pk;
    pk.x = (uint)v[0] | ((uint)v[1] << 16);
    pk.y = (uint)v[2] | ((uint)v[3] << 16);
    pk.z = (uint)v[4] | ((uint)v[5] << 16);
    pk.w = (uint)v[6] | ((uint)v[7] << 16);
    *(uint4*)(ob + (long)n * CIN + c8 * 8) = pk;
  }
}

// ---------------- K0b: fp32 -> bf16 flat convert (qkv_w) ----------------
__global__ __launch_bounds__(256) void k0_cvtw(const float* __restrict__ w,
                                               ushort* __restrict__ wb, int nelem) {
  int i = (blockIdx.x * 256 + threadIdx.x) * 4;
  if (i + 3 < nelem) {
    float4 f = *(const float4*)(w + i);
    ushort4 o;
    o.x = f2bf(f.x); o.y = f2bf(f.y); o.z = f2bf(f.z); o.w = f2bf(f.w);
    *(ushort4*)(wb + i) = o;
  }
}

// ---------------- GEMM NT: D[M,HW] = A[M,192] * B[HW,192]^T ----------------
// Mt=192, Nt=64, Kt=64, 512 thr (8 waves = 4m x 2n), LDS rows padded to 144B.
template <typename TOut>
__global__ __launch_bounds__(512, 4) void gemm_nt(const ushort* __restrict__ A, long a_bstride,
                                                  const ushort* __restrict__ B, long b_bstride,
                                                  TOut* __restrict__ D, long d_bstride,
                                                  int mtiles) {
  __shared__ ushort lds[18432];  // A: 192*144B = 27648, B: 64*144B = 9216
  int idx = blockIdx.x;
  int ntile = idx & 1023;
  int bm = idx >> 10;
  int mtile = bm % mtiles;
  int b = bm / mtiles;
  int tid = threadIdx.x;
  int lane = tid & 63;
  int wv = tid >> 6;
  int wm = wv >> 1, wn = wv & 1;
  int lanelo = lane & 15, laneq = lane >> 4;

  const ushort* Ab = A + a_bstride * b + (long)mtile * 192 * 192;
  const ushort* Bb = B + b_bstride * b + (long)ntile * 64 * 192;

  f32x4 acc[3][2] = {};

  for (int kit = 0; kit < 3; ++kit) {
#pragma unroll
    for (int i = 0; i < 5; ++i) {
      int wbase = i * 512 + wv * 64;
      if (wbase < 2304) {
        int c = wbase + lane;
        bool isA = c < 1728;
        int local = isA ? c : c - 1728;
        int row = local / 9;
        int sub = local % 9;
        if (sub < 8) {
          const ushort* g = (isA ? Ab : Bb) + row * 192 + kit * 64 + sub * 8;
          async16((char*)lds + wbase * 16, g);
        }
      }
    }
    __syncthreads();
#pragma unroll
    for (int ks = 0; ks < 2; ++ks) {
      bf16x8 af[3], bf[2];
#pragma unroll
      for (int mt = 0; mt < 3; ++mt) {
        int m = wm * 48 + mt * 16 + lanelo;
        af[mt] = *(const bf16x8*)((const char*)lds + m * 144 + ks * 64 + laneq * 16);
      }
#pragma unroll
      for (int nt = 0; nt < 2; ++nt) {
        int n = wn * 32 + nt * 16 + lanelo;
        bf[nt] = *(const bf16x8*)((const char*)lds + 27648 + n * 144 + ks * 64 + laneq * 16);
      }
#pragma unroll
      for (int mt = 0; mt < 3; ++mt)
#pragma unroll
        for (int nt = 0; nt < 2; ++nt)
          acc[mt][nt] = __builtin_amdgcn_mfma_f32_16x16x32_bf16(af[mt], bf[nt], acc[mt][nt], 0, 0, 0);
    }
    __syncthreads();
  }

  TOut* Db = D + d_bstride * b;
  int colb = ntile * 64 + wn * 32 + lanelo;
#pragma unroll
  for (int mt = 0; mt < 3; ++mt)
#pragma unroll
    for (int nt = 0; nt < 2; ++nt)
#pragma unroll
      for (int r = 0; r < 4; ++r) {
        long row = (long)(mtile * 192 + wm * 48 + mt * 16 + laneq * 4 + r);
        float v = acc[mt][nt][r];
        if constexpr (sizeof(TOut) == 2)
          Db[row * HWSZ + colb + nt * 16] = f2bf(v);
        else
          Db[row * HWSZ + colb + nt * 16] = v;
      }
}

// ---------------- K2a: depthwise 3x3 on q,k channels (c-major out) + sq-norms ---------
__global__ __launch_bounds__(256) void k2_qk(const ushort* __restrict__ qkv,
                                             ushort* __restrict__ qkdw,
                                             float* __restrict__ sqn,
                                             const float* __restrict__ dww) {
  __shared__ uint row_lds[6 * 130];
  int id = blockIdx.x;
  int yt = id & 63;
  int bc = id >> 6;
  int c = bc % CQK;
  int b = bc / CQK;
  int y0 = yt * 4;
  int tid = threadIdx.x;
  const uint* src = (const uint*)qkv + ((long)(b * C3 + c) * HWSZ >> 1);
  for (int i = tid; i < 780; i += 256) {
    int r = i / 130, wx = i % 130;
    int gy = y0 - 1 + r;
    int gw = wx - 1;
    uint v = 0;
    if (gy >= 0 && gy < 256 && gw >= 0 && gw < 128) v = src[gy * 128 + gw];
    row_lds[i] = v;
  }
  float w9[9];
#pragma unroll
  for (int j = 0; j < 9; ++j) w9[j] = dww[c * 9 + j];
  __syncthreads();
  float ss = 0.f;
  uint* dst = (uint*)qkdw + ((long)(b * CQK + c) * HWSZ >> 1);
#pragma unroll
  for (int p = 0; p < 2; ++p) {
    int pi = tid + p * 256;
    int yl = pi >> 7, xp = pi & 127;
    float o0 = 0.f, o1 = 0.f;
#pragma unroll
    for (int dy = 0; dy < 3; ++dy) {
      int base = (yl + dy) * 130 + xp;
      uint u0 = row_lds[base], u1 = row_lds[base + 1], u2 = row_lds[base + 2];
      float f0 = bfhi(u0), f1 = bflo(u1), f2 = bfhi(u1), f3 = bflo(u2);
      o0 += w9[dy * 3 + 0] * f0 + w9[dy * 3 + 1] * f1 + w9[dy * 3 + 2] * f2;
      o1 += w9[dy * 3 + 0] * f1 + w9[dy * 3 + 1] * f2 + w9[dy * 3 + 2] * f3;
    }
    ss += o0 * o0 + o1 * o1;
    dst[(y0 + yl) * 128 + xp] = (uint)f2bf(o0) | ((uint)f2bf(o1) << 16);
  }
#pragma unroll
  for (int off = 32; off; off >>= 1) ss += __shfl_down(ss, off);
  if ((tid & 63) == 0) atomicAdd(sqn + b * CQK + c, ss);
}

// ---------------- K2b: depthwise 3x3 on v channels, output transposed [n][c] ----------
__global__ __launch_bounds__(256) void k2_v(const ushort* __restrict__ qkv,
                                            ushort* __restrict__ vT,
                                            const float* __restrict__ dww) {
  __shared__ uint in_lds[9792];        // 96c x 3y x 34 u32
  __shared__ float wlds[864];
  __shared__ ushort out_lds[64 * 104]; // [x_local][c] stride 104
  int id = blockIdx.x;
  int cg = id & 1;
  int xt = (id >> 1) & 3;
  int y = (id >> 3) & 255;
  int b = id >> 11;
  int x0 = xt * 64;
  int tid = threadIdx.x;
  int cbase = CQK + cg * 96;
  const uint* src = (const uint*)qkv + ((long)b * C3 * HWSZ >> 1);
  for (int i = tid; i < 9792; i += 256) {
    int seg = i / 34, w = i % 34;
    int c = seg / 3, dy = seg % 3;
    int gy = y + dy - 1;
    int gwu = (x0 >> 1) - 1 + w;
    uint v = 0;
    if (gy >= 0 && gy < 256 && gwu >= 0 && gwu < 128)
      v = src[(long)(cbase + c) * (HWSZ / 2) + gy * 128 + gwu];
    in_lds[i] = v;
  }
  for (int i = tid; i < 864; i += 256) wlds[i] = dww[cbase * 9 + i];
  __syncthreads();
#pragma unroll
  for (int j = 0; j < 12; ++j) {
    int flat = tid + j * 256;
    int clo = flat & 31;
    int q = flat >> 5;             // 0..95
    int xp = q & 31;
    int c = (q >> 5) * 32 + clo;   // 0..95
    float o0 = 0.f, o1 = 0.f;
#pragma unroll
    for (int dy = 0; dy < 3; ++dy) {
      int base = (c * 3 + dy) * 34 + xp;
      uint u0 = in_lds[base], u1 = in_lds[base + 1], u2 = in_lds[base + 2];
      float f0 = bfhi(u0), f1 = bflo(u1), f2 = bfhi(u1), f3 = bflo(u2);
      float wa = wlds[c * 9 + dy * 3 + 0], wbv = wlds[c * 9 + dy * 3 + 1], wc = wlds[c * 9 + dy * 3 + 2];
      o0 += wa * f0 + wbv * f1 + wc * f2;
      o1 += wa * f1 + wbv * f2 + wc * f3;
    }
    out_lds[(2 * xp + 0) * 104 + c] = f2bf(o0);
    out_lds[(2 * xp + 1) * 104 + c] = f2bf(o1);
  }
  __syncthreads();
  ushort* dst = vT + (long)b * HWSZ * CIN + (long)(y * 256 + x0) * CIN + cg * 96;
  for (int i = tid; i < 768; i += 256) {
    int nl = i / 12, ch = i % 12;
    uint4 v = *(const uint4*)(out_lds + nl * 104 + ch * 8);
    *(uint4*)(dst + (long)nl * CIN + ch * 8) = v;
  }
}

// ---------------- K3a: raw attention logits (per head, reduce over n) ----------------
__global__ __launch_bounds__(256, 4) void k3_attn(const ushort* __restrict__ qkdw,
                                                  float* __restrict__ raw) {
  __shared__ ushort qk_lds[96 * 136];  // rows padded to 272B
  int id = blockIdx.x;
  int chunk = id & 15;
  int bh = id >> 4;
  int b = bh >> 2, h = bh & 3;
  int tid = threadIdx.x;
  int lane = tid & 63, wv = tid >> 6;
  int lanelo = lane & 15, laneq = lane >> 4;
  f32x4 acc[3][3] = {};
  long kbase0 = (long)chunk * 4096;
  for (int it = 0; it < 32; ++it) {
    long kb = kbase0 + it * 128;
#pragma unroll
    for (int i = 0; i < 7; ++i) {
      int wbase = i * 256 + wv * 64;
      if (wbase < 1632) {
        int c = wbase + lane;
        if (c < 1632) {
          int row = c / 17, sub = c % 17;
          if (sub < 16) {
            int ch = (row < 48) ? (h * 48 + row) : (192 + h * 48 + row - 48);
            const ushort* g = qkdw + (long)(b * CQK + ch) * HWSZ + kb + sub * 8;
            async16((char*)qk_lds + wbase * 16, g);
          }
        }
      }
    }
    __syncthreads();
    bf16x8 af[3], bf[3];
#pragma unroll
    for (int mt = 0; mt < 3; ++mt)
      af[mt] = *(const bf16x8*)((const char*)qk_lds + (mt * 16 + lanelo) * 272 + wv * 64 + laneq * 16);
#pragma unroll
    for (int et = 0; et < 3; ++et)
      bf[et] = *(const bf16x8*)((const char*)qk_lds + (48 + et * 16 + lanelo) * 272 + wv * 64 + laneq * 16);
#pragma unroll
    for (int mt = 0; mt < 3; ++mt)
#pragma unroll
      for (int et = 0; et < 3; ++et)
        acc[mt][et] = __builtin_amdgcn_mfma_f32_16x16x32_bf16(af[mt], bf[et], acc[mt][et], 0, 0, 0);
    __syncthreads();
  }
  float* rb = raw + (long)bh * 2304;
#pragma unroll
  for (int mt = 0; mt < 3; ++mt)
#pragma unroll
    for (int et = 0; et < 3; ++et)
#pragma unroll
      for (int r = 0; r < 4; ++r) {
        int d = mt * 16 + laneq * 4 + r;
        int e = et * 16 + lanelo;
        atomicAdd(rb + d * 48 + e, acc[mt][et][r]);
      }
}

// ---------------- K3b: normalize + softmax + fold proj_w into M ----------------
__global__ __launch_bounds__(256) void k3_soft(const float* __restrict__ raw,
                                               const float* __restrict__ sqn,
                                               const float* __restrict__ temp,
                                               const float* __restrict__ projw,
                                               ushort* __restrict__ M) {
  __shared__ float attn[48 * 48];
  __shared__ float iq[48], ik[48];
  int bh = blockIdx.x;
  int b = bh >> 2, h = bh & 3;
  int tid = threadIdx.x;
  if (tid < 48) {
    float nq = sqrtf(sqn[b * CQK + h * 48 + tid]);
    iq[tid] = 1.f / fmaxf(nq, 1e-12f);
  } else if (tid < 96) {
    int e = tid - 48;
    float nk = sqrtf(sqn[b * CQK + 192 + h * 48 + e]);
    ik[e] = 1.f / fmaxf(nk, 1e-12f);
  }
  __syncthreads();
  float t = temp[h];
  for (int i = tid; i < 2304; i += 256) {
    int d = i / 48, e = i % 48;
    attn[i] = raw[(long)bh * 2304 + i] * iq[d] * ik[e] * t;
  }
  __syncthreads();
  if (tid < 48) {
    float mx = -1e30f;
    for (int e = 0; e < 48; ++e) mx = fmaxf(mx, attn[tid * 48 + e]);
    float s = 0.f;
    for (int e = 0; e < 48; ++e) {
      float v = expf(attn[tid * 48 + e] - mx);
      attn[tid * 48 + e] = v;
      s += v;
    }
    float inv = 1.f / s;
    for (int e = 0; e < 48; ++e) attn[tid * 48 + e] *= inv;
  }
  __syncthreads();
  ushort* Mb = M + (long)b * 192 * 192;
  for (int i = tid; i < 192 * 48; i += 256) {
    int cp = i / 48, e = i % 48;
    const float* pw = projw + (long)cp * 192 + h * 48;
    float s = 0.f;
#pragma unroll 4
    for (int d = 0; d < 48; ++d) s += pw[d] * attn[d * 48 + e];
    Mb[(long)cp * 192 + h * 48 + e] = f2bf(s);
  }
}

extern "C" void kernel_launch(void* const* d_in, const int* in_sizes, int n_in,
                              void* d_out, int out_size, void* d_ws, size_t ws_size,
                              hipStream_t stream) {
  const float* x = (const float*)d_in[0];
  const float* qkv_w = (const float*)d_in[1];
  const float* dw_w = (const float*)d_in[2];
  const float* temp = (const float*)d_in[3];
  const float* proj_w = (const float*)d_in[4];

  char* ws = (char*)d_ws;
  ushort* xT = (ushort*)(ws);                      // 100,663,296 B ; reused as vT
  ushort* QKV = (ushort*)(ws + 100663296L);        // 301,989,888 B
  ushort* qkdw = (ushort*)(ws + 402653184L);       // 201,326,592 B
  ushort* wbf = (ushort*)(ws + 603979776L);        // 221,184 B
  ushort* Mbf = (ushort*)(ws + 604200960L);        // 294,912 B
  float* sqn = (float*)(ws + 604495872L);          // 6,144 B
  float* raw = (float*)(ws + 604502016L);          // 147,456 B

  hipMemsetAsync(sqn, 0, 153600, stream);  // sqn + raw (adjacent)

  k0_transpose<<<4096, 256, 0, stream>>>(x, xT);
  k0_cvtw<<<108, 256, 0, stream>>>(qkv_w, wbf, 110592);
  gemm_nt<ushort><<<12288, 512, 0, stream>>>(wbf, 0L, xT, (long)HWSZ * CIN, QKV, (long)C3 * HWSZ, 3);
  k2_qk<<<98304, 256, 0, stream>>>(QKV, qkdw, sqn, dw_w);
  k2_v<<<8192, 256, 0, stream>>>(QKV, xT, dw_w);  // overwrites xT with vT (K1 done)
  k3_attn<<<256, 256, 0, stream>>>(qkdw, raw);
  k3_soft<<<16, 256, 0, stream>>>(raw, sqn, temp, proj_w, Mbf);
  gemm_nt<float><<<4096, 512, 0, stream>>>(Mbf, (long)192 * 192, xT, (long)HWSZ * CIN,
                                           (float*)d_out, (long)CIN * HWSZ, 1);
}

// Round 2
// 1158.279 us; speedup vs baseline: 1.4241x; 1.4241x over previous
//
#include <hip/hip_runtime.h>

typedef unsigned int uint;
typedef unsigned short ushort;
typedef __attribute__((ext_vector_type(8))) short bf16x8;
typedef __attribute__((ext_vector_type(4))) float f32x4;

#define HWSZ 65536
#define CIN 192
#define C3 576
#define CQK 384

typedef __attribute__((address_space(1))) const void gvoid_c;
typedef __attribute__((address_space(3))) void lvoid;

__device__ __forceinline__ void async16(void* l, const void* g) {
  __builtin_amdgcn_global_load_lds((gvoid_c*)g, (lvoid*)l, 16, 0, 0);
}

__device__ __forceinline__ ushort f2bf(float f) {
  uint u = __float_as_uint(f);
  return (ushort)((u + 0x7fffu + ((u >> 16) & 1u)) >> 16);
}
__device__ __forceinline__ float bflo(uint u) { return __uint_as_float(u << 16); }
__device__ __forceinline__ float bfhi(uint u) { return __uint_as_float(u & 0xffff0000u); }

// ---------------- K0a: x fp32 [b][c][n] -> bf16 [b][n][c], LDS-staged ----------------
// lds layout [c][n], row stride 66 ushorts => phase2 banks = (c + n/2) % 32 (2-way max).
__global__ __launch_bounds__(256) void k0_transpose(const float* __restrict__ x,
                                                    ushort* __restrict__ xT) {
  __shared__ ushort lds_t[192 * 66];
  int id = blockIdx.x;
  int n0 = (id & 1023) << 6;
  int b = id >> 10;
  int tid = threadIdx.x;
  int nl = tid & 63;
  int cq = tid >> 6;
  const float* xb = x + (long)b * CIN * HWSZ + n0;
#pragma unroll 4
  for (int j = 0; j < 48; ++j) {
    int c = cq + 4 * j;
    lds_t[c * 66 + nl] = f2bf(xb[(long)c * HWSZ + nl]);
  }
  __syncthreads();
  ushort* ob = xT + (long)b * HWSZ * CIN + (long)n0 * CIN;
  int l = tid & 63, w = tid >> 6;
#pragma unroll
  for (int jj = 0; jj < 6; ++jj) {
    int n = w * 16 + (l & 15);
    int m = jj * 4 + (l >> 4);
    int cb = m * 8;
    ushort v[8];
#pragma unroll
    for (int k = 0; k < 8; ++k) v[k] = lds_t[(cb + k) * 66 + n];
    uint4 pk;
    pk.x = (uint)v[0] | ((uint)v[1] << 16);
    pk.y = (uint)v[2] | ((uint)v[3] << 16);
    pk.z = (uint)v[4] | ((uint)v[5] << 16);
    pk.w = (uint)v[6] | ((uint)v[7] << 16);
    *(uint4*)(ob + (long)n * CIN + cb) = pk;
  }
}

// ---------------- K0b: fp32 -> bf16 flat convert (qkv_w) ----------------
__global__ __launch_bounds__(256) void k0_cvtw(const float* __restrict__ w,
                                               ushort* __restrict__ wb, int nelem) {
  int i = (blockIdx.x * 256 + threadIdx.x) * 4;
  if (i + 3 < nelem) {
    float4 f = *(const float4*)(w + i);
    ushort4 o;
    o.x = f2bf(f.x); o.y = f2bf(f.y); o.z = f2bf(f.z); o.w = f2bf(f.w);
    *(ushort4*)(wb + i) = o;
  }
}

// ---------------- GEMM NT: D[M,HW] = A[M,192] * B[HW,192]^T ----------------
template <typename TOut>
__global__ __launch_bounds__(512, 4) void gemm_nt(const ushort* __restrict__ A, long a_bstride,
                                                  const ushort* __restrict__ B, long b_bstride,
                                                  TOut* __restrict__ D, long d_bstride,
                                                  int mtiles) {
  __shared__ ushort lds[18432];  // A: 192*144B = 27648B, B: 64*144B = 9216B
  int idx = blockIdx.x;
  int ntile = idx & 1023;
  int bm = idx >> 10;
  int mtile = bm % mtiles;
  int b = bm / mtiles;
  int tid = threadIdx.x;
  int lane = tid & 63;
  int wv = tid >> 6;
  int wm = wv >> 1, wn = wv & 1;
  int lanelo = lane & 15, laneq = lane >> 4;

  const ushort* Ab = A + a_bstride * b + (long)mtile * 192 * 192;
  const ushort* Bb = B + b_bstride * b + (long)ntile * 64 * 192;

  f32x4 acc[3][2] = {};

  for (int kit = 0; kit < 3; ++kit) {
#pragma unroll
    for (int i = 0; i < 5; ++i) {
      int wbase = i * 512 + wv * 64;
      if (wbase < 2304) {
        int c = wbase + lane;
        bool isA = c < 1728;
        int local = isA ? c : c - 1728;
        int row = local / 9;
        int sub = local % 9;
        if (sub < 8) {
          const ushort* g = (isA ? Ab : Bb) + row * 192 + kit * 64 + sub * 8;
          async16((char*)lds + wbase * 16, g);
        }
      }
    }
    __syncthreads();
#pragma unroll
    for (int ks = 0; ks < 2; ++ks) {
      bf16x8 af[3], bf[2];
#pragma unroll
      for (int mt = 0; mt < 3; ++mt) {
        int m = wm * 48 + mt * 16 + lanelo;
        af[mt] = *(const bf16x8*)((const char*)lds + m * 144 + ks * 64 + laneq * 16);
      }
#pragma unroll
      for (int nt = 0; nt < 2; ++nt) {
        int n = wn * 32 + nt * 16 + lanelo;
        bf[nt] = *(const bf16x8*)((const char*)lds + 27648 + n * 144 + ks * 64 + laneq * 16);
      }
#pragma unroll
      for (int mt = 0; mt < 3; ++mt)
#pragma unroll
        for (int nt = 0; nt < 2; ++nt)
          acc[mt][nt] = __builtin_amdgcn_mfma_f32_16x16x32_bf16(af[mt], bf[nt], acc[mt][nt], 0, 0, 0);
    }
    __syncthreads();
  }

  TOut* Db = D + d_bstride * b;
  int colb = ntile * 64 + wn * 32 + lanelo;
#pragma unroll
  for (int mt = 0; mt < 3; ++mt)
#pragma unroll
    for (int nt = 0; nt < 2; ++nt)
#pragma unroll
      for (int r = 0; r < 4; ++r) {
        long row = (long)(mtile * 192 + wm * 48 + mt * 16 + laneq * 4 + r);
        float v = acc[mt][nt][r];
        if constexpr (sizeof(TOut) == 2)
          Db[row * HWSZ + colb + nt * 16] = f2bf(v);
        else
          Db[row * HWSZ + colb + nt * 16] = v;
      }
}

// ---------------- K2a v2: depthwise 3x3 on q,k channels + sq-norm partials ----------
// block = (b, c, ytile of 32 rows); 16 u32 outputs/thread; NO atomics.
__global__ __launch_bounds__(256) void k2_qk(const ushort* __restrict__ qkv,
                                             ushort* __restrict__ qkdw,
                                             float* __restrict__ sqp,
                                             const float* __restrict__ dww) {
  __shared__ uint row_lds[34 * 132];  // 17952 B
  __shared__ float red[4];
  int id = blockIdx.x;
  int yt = id & 7;
  int bc = id >> 3;
  int c = bc % CQK;
  int b = bc / CQK;
  int y0 = yt * 32;
  int tid = threadIdx.x;
  const uint* src = (const uint*)qkv + ((long)(b * C3 + c) * HWSZ >> 1);
  for (int i = tid; i < 4488; i += 256) {
    int r = i / 132, wx = i % 132;
    int gy = y0 - 1 + r;
    uint v = 0;
    if (gy >= 0 && gy < 256 && wx >= 1 && wx <= 128) v = src[gy * 128 + wx - 1];
    row_lds[i] = v;
  }
  float w9[9];
#pragma unroll
  for (int j = 0; j < 9; ++j) w9[j] = dww[c * 9 + j];
  __syncthreads();
  int row = tid >> 3;        // 0..31
  int xp0 = (tid & 7) * 16;  // u32 col base
  float ss = 0.f;
  uint* dst = (uint*)qkdw + ((long)(b * CQK + c) * HWSZ >> 1) + (y0 + row) * 128 + xp0;
#pragma unroll
  for (int ch = 0; ch < 4; ++ch) {
    float o0[4] = {0.f, 0.f, 0.f, 0.f}, o1[4] = {0.f, 0.f, 0.f, 0.f};
#pragma unroll
    for (int dy = 0; dy < 3; ++dy) {
      const uint* L = &row_lds[(row + dy) * 132 + xp0 + ch * 4];
      uint4 q4 = *(const uint4*)L;
      uint2 q2 = *(const uint2*)(L + 4);
      uint u[6] = {q4.x, q4.y, q4.z, q4.w, q2.x, q2.y};
      float wa = w9[dy * 3 + 0], wb_ = w9[dy * 3 + 1], wc = w9[dy * 3 + 2];
#pragma unroll
      for (int j = 0; j < 4; ++j) {
        float f0 = bfhi(u[j]), f1 = bflo(u[j + 1]), f2 = bfhi(u[j + 1]), f3 = bflo(u[j + 2]);
        o0[j] += wa * f0 + wb_ * f1 + wc * f2;
        o1[j] += wa * f1 + wb_ * f2 + wc * f3;
      }
    }
    uint4 pk;
    pk.x = (uint)f2bf(o0[0]) | ((uint)f2bf(o1[0]) << 16);
    pk.y = (uint)f2bf(o0[1]) | ((uint)f2bf(o1[1]) << 16);
    pk.z = (uint)f2bf(o0[2]) | ((uint)f2bf(o1[2]) << 16);
    pk.w = (uint)f2bf(o0[3]) | ((uint)f2bf(o1[3]) << 16);
#pragma unroll
    for (int j = 0; j < 4; ++j) ss += o0[j] * o0[j] + o1[j] * o1[j];
    *(uint4*)(dst + ch * 4) = pk;
  }
#pragma unroll
  for (int off = 32; off; off >>= 1) ss += __shfl_down(ss, off);
  if ((tid & 63) == 0) red[tid >> 6] = ss;
  __syncthreads();
  if (tid == 0) sqp[(long)(b * CQK + c) * 8 + yt] = red[0] + red[1] + red[2] + red[3];
}

// ---------------- K2b: depthwise 3x3 on v channels, output transposed [n][c] ----------
__global__ __launch_bounds__(256) void k2_v(const ushort* __restrict__ qkv,
                                            ushort* __restrict__ vT,
                                            const float* __restrict__ dww) {
  __shared__ uint in_lds[9792];        // 96c x 3y x 34 u32
  __shared__ float wlds[864];
  __shared__ ushort out_lds[64 * 104]; // [x_local][c] stride 104
  int id = blockIdx.x;
  int cg = id & 1;
  int xt = (id >> 1) & 3;
  int y = (id >> 3) & 255;
  int b = id >> 11;
  int x0 = xt * 64;
  int tid = threadIdx.x;
  int cbase = CQK + cg * 96;
  const uint* src = (const uint*)qkv + ((long)b * C3 * HWSZ >> 1);
  for (int i = tid; i < 9792; i += 256) {
    int seg = i / 34, w = i % 34;
    int c = seg / 3, dy = seg % 3;
    int gy = y + dy - 1;
    int gwu = (x0 >> 1) - 1 + w;
    uint v = 0;
    if (gy >= 0 && gy < 256 && gwu >= 0 && gwu < 128)
      v = src[(long)(cbase + c) * (HWSZ / 2) + gy * 128 + gwu];
    in_lds[i] = v;
  }
  for (int i = tid; i < 864; i += 256) wlds[i] = dww[cbase * 9 + i];
  __syncthreads();
#pragma unroll
  for (int j = 0; j < 12; ++j) {
    int flat = tid + j * 256;
    int clo = flat & 31;
    int q = flat >> 5;             // 0..95
    int xp = q & 31;
    int c = (q >> 5) * 32 + clo;   // 0..95
    float o0 = 0.f, o1 = 0.f;
#pragma unroll
    for (int dy = 0; dy < 3; ++dy) {
      int base = (c * 3 + dy) * 34 + xp;
      uint u0 = in_lds[base], u1 = in_lds[base + 1], u2 = in_lds[base + 2];
      float f0 = bfhi(u0), f1 = bflo(u1), f2 = bfhi(u1), f3 = bflo(u2);
      float wa = wlds[c * 9 + dy * 3 + 0], wbv = wlds[c * 9 + dy * 3 + 1], wc = wlds[c * 9 + dy * 3 + 2];
      o0 += wa * f0 + wbv * f1 + wc * f2;
      o1 += wa * f1 + wbv * f2 + wc * f3;
    }
    out_lds[(2 * xp + 0) * 104 + c] = f2bf(o0);
    out_lds[(2 * xp + 1) * 104 + c] = f2bf(o1);
  }
  __syncthreads();
  ushort* dst = vT + (long)b * HWSZ * CIN + (long)(y * 256 + x0) * CIN + cg * 96;
  for (int i = tid; i < 768; i += 256) {
    int nl = i / 12, ch = i % 12;
    uint4 v = *(const uint4*)(out_lds + nl * 104 + ch * 8);
    *(uint4*)(dst + (long)nl * CIN + ch * 8) = v;
  }
}

// ---------------- K3a v2: attention logit partials (32 chunks, plain stores) --------
__global__ __launch_bounds__(256, 4) void k3_attn(const ushort* __restrict__ qkdw,
                                                  float* __restrict__ rawp) {
  __shared__ ushort qk_lds[96 * 136];  // rows padded to 272B
  int id = blockIdx.x;
  int chunk = id & 31;
  int bh = id >> 5;
  int b = bh >> 2, h = bh & 3;
  int tid = threadIdx.x;
  int lane = tid & 63, wv = tid >> 6;
  int lanelo = lane & 15, laneq = lane >> 4;
  f32x4 acc[3][3] = {};
  long kbase0 = (long)chunk * 2048;
  for (int it = 0; it < 16; ++it) {
    long kb = kbase0 + it * 128;
#pragma unroll
    for (int i = 0; i < 7; ++i) {
      int wbase = i * 256 + wv * 64;
      if (wbase < 1632) {
        int cc = wbase + lane;
        if (cc < 1632) {
          int row = cc / 17, sub = cc % 17;
          if (sub < 16) {
            int chn = (row < 48) ? (h * 48 + row) : (192 + h * 48 + row - 48);
            const ushort* g = qkdw + (long)(b * CQK + chn) * HWSZ + kb + sub * 8;
            async16((char*)qk_lds + wbase * 16, g);
          }
        }
      }
    }
    __syncthreads();
    bf16x8 af[3], bf[3];
#pragma unroll
    for (int mt = 0; mt < 3; ++mt)
      af[mt] = *(const bf16x8*)((const char*)qk_lds + (mt * 16 + lanelo) * 272 + wv * 64 + laneq * 16);
#pragma unroll
    for (int et = 0; et < 3; ++et)
      bf[et] = *(const bf16x8*)((const char*)qk_lds + (48 + et * 16 + lanelo) * 272 + wv * 64 + laneq * 16);
#pragma unroll
    for (int mt = 0; mt < 3; ++mt)
#pragma unroll
      for (int et = 0; et < 3; ++et)
        acc[mt][et] = __builtin_amdgcn_mfma_f32_16x16x32_bf16(af[mt], bf[et], acc[mt][et], 0, 0, 0);
    __syncthreads();
  }
  float* rb = rawp + ((long)bh * 32 + chunk) * 2304;
#pragma unroll
  for (int mt = 0; mt < 3; ++mt)
#pragma unroll
    for (int et = 0; et < 3; ++et)
#pragma unroll
      for (int r = 0; r < 4; ++r) {
        int d = mt * 16 + laneq * 4 + r;
        int e = et * 16 + lanelo;
        rb[d * 48 + e] = acc[mt][et][r];
      }
}

// ---------------- K3b v2: reduce partials + normalize + softmax + fold proj_w -------
__global__ __launch_bounds__(256) void k3_soft(const float* __restrict__ rawp,
                                               const float* __restrict__ sqp,
                                               const float* __restrict__ temp,
                                               const float* __restrict__ projw,
                                               ushort* __restrict__ M) {
  __shared__ float attn[48 * 48];
  __shared__ float iq[48], ik[48];
  int bh = blockIdx.x;
  int b = bh >> 2, h = bh & 3;
  int tid = threadIdx.x;
  if (tid < 48) {
    const float* p = sqp + (long)(b * CQK + h * 48 + tid) * 8;
    float s = 0.f;
#pragma unroll
    for (int k = 0; k < 8; ++k) s += p[k];
    iq[tid] = 1.f / fmaxf(sqrtf(s), 1e-12f);
  } else if (tid < 96) {
    int e = tid - 48;
    const float* p = sqp + (long)(b * CQK + 192 + h * 48 + e) * 8;
    float s = 0.f;
#pragma unroll
    for (int k = 0; k < 8; ++k) s += p[k];
    ik[e] = 1.f / fmaxf(sqrtf(s), 1e-12f);
  }
  __syncthreads();
  float t = temp[h];
  for (int i = tid; i < 2304; i += 256) {
    float s = 0.f;
    const float* rp = rawp + (long)bh * 32 * 2304 + i;
#pragma unroll 8
    for (int ch = 0; ch < 32; ++ch) s += rp[ch * 2304];
    int d = i / 48, e = i % 48;
    attn[i] = s * iq[d] * ik[e] * t;
  }
  __syncthreads();
  if (tid < 48) {
    float mx = -1e30f;
    for (int e = 0; e < 48; ++e) mx = fmaxf(mx, attn[tid * 48 + e]);
    float s = 0.f;
    for (int e = 0; e < 48; ++e) {
      float v = expf(attn[tid * 48 + e] - mx);
      attn[tid * 48 + e] = v;
      s += v;
    }
    float inv = 1.f / s;
    for (int e = 0; e < 48; ++e) attn[tid * 48 + e] *= inv;
  }
  __syncthreads();
  ushort* Mb = M + (long)b * 192 * 192;
  for (int i = tid; i < 192 * 48; i += 256) {
    int cp = i / 48, e = i % 48;
    const float* pw = projw + (long)cp * 192 + h * 48;
    float s = 0.f;
#pragma unroll 4
    for (int d = 0; d < 48; ++d) s += pw[d] * attn[d * 48 + e];
    Mb[(long)cp * 192 + h * 48 + e] = f2bf(s);
  }
}

extern "C" void kernel_launch(void* const* d_in, const int* in_sizes, int n_in,
                              void* d_out, int out_size, void* d_ws, size_t ws_size,
                              hipStream_t stream) {
  const float* x = (const float*)d_in[0];
  const float* qkv_w = (const float*)d_in[1];
  const float* dw_w = (const float*)d_in[2];
  const float* temp = (const float*)d_in[3];
  const float* proj_w = (const float*)d_in[4];

  char* ws = (char*)d_ws;
  ushort* xT = (ushort*)(ws);                      // 100,663,296 B ; reused as vT
  ushort* QKV = (ushort*)(ws + 100663296L);        // 301,989,888 B
  ushort* qkdw = (ushort*)(ws + 402653184L);       // 201,326,592 B
  ushort* wbf = (ushort*)(ws + 603979776L);        // 221,184 B
  ushort* Mbf = (ushort*)(ws + 604200960L);        // 294,912 B
  float* sqp = (float*)(ws + 604495872L);          // 49,152 B
  float* rawp = (float*)(ws + 604545024L);         // 4,718,592 B

  k0_transpose<<<4096, 256, 0, stream>>>(x, xT);
  k0_cvtw<<<108, 256, 0, stream>>>(qkv_w, wbf, 110592);
  gemm_nt<ushort><<<12288, 512, 0, stream>>>(wbf, 0L, xT, (long)HWSZ * CIN, QKV, (long)C3 * HWSZ, 3);
  k2_qk<<<12288, 256, 0, stream>>>(QKV, qkdw, sqp, dw_w);
  k2_v<<<8192, 256, 0, stream>>>(QKV, xT, dw_w);  // overwrites xT with vT (gemm done)
  k3_attn<<<512, 256, 0, stream>>>(qkdw, rawp);
  k3_soft<<<16, 256, 0, stream>>>(rawp, sqp, temp, proj_w, Mbf);
  gemm_nt<float><<<4096, 512, 0, stream>>>(Mbf, (long)192 * 192, xT, (long)HWSZ * CIN,
                                           (float*)d_out, (long)CIN * HWSZ, 1);
}